// Round 2
// baseline (511.709 us; speedup 1.0000x reference)
//
#include <hip/hip_runtime.h>
#include <hip/hip_bf16.h>

// 2-layer GCN + mean pool. N=100000, E=1600000, G=128. dims 3 -> 64 -> 128.
//   h1  = relu( (A_hat x) @ W1 + b1 )        -- aggregate 3-dim x, then tiny GEMM
//   out = (mean_g (A_hat h1)) @ W2 + b2      -- aggregate 64-dim h1, pool, tiny GEMM
//
// R12 resubmit (previous bench was an infra failure, no counters returned):
//   * k_gather2: 8-lane groups x uint4 (16B) loads. One dwordx4 instruction
//     fetches 8 edges' 128B hs1 rows (1KB) vs 2 (256B) before. 4x fewer VMEM
//     instrs, 4x less duplicated meta-decode VALU, 4x bytes in flight.
//     Register g-monotone accumulation preserved per 8-lane group (stride-8
//     subsequence of dst-sorted stream stays g-monotone).
//   * k_split: serial 391-iter thread-0 scan -> 512-entry parallel LDS scan.
//   * k_count: TILE_C 16384 -> 4096 (391 blocks, full CU coverage).
//
// DTYPE-ADAPTIVE: k_detect probes raw bits: flags[0]=bf16?, flags[1]=int64?

typedef __hip_bfloat16 bf16;
#define NGRAPH 128
#define NSLICE 8
#define TILE_C 4096
#define TILE_S 4096
#define SCAP   12288 // k_sort LDS stage capacity (mean 4096+256, >60 sigma)

__device__ __forceinline__ float b2f(bf16 v) { return __bfloat162float(v); }
__device__ __forceinline__ float bfb(unsigned short u) {
    return __uint_as_float((unsigned)u << 16);
}
__device__ __forceinline__ float fld(const void* p, long long i, int isbf) {
    return isbf ? b2f(((const bf16*)p)[i]) : ((const float*)p)[i];
}
__device__ __forceinline__ int ild(const void* p, long long i, int is64) {
    return is64 ? (int)((const long long*)p)[i] : ((const int*)p)[i];
}

// ---- dtype probe --------------------------------------------------------
__global__ void k_detect(const void* x, const void* ei, int* flags) {
    if (threadIdx.x != 0 || blockIdx.x != 0) return;
    const unsigned short* u = (const unsigned short*)x;
    int good = 0;
    for (int k = 0; k < 128; ++k) {
        int e = (u[2 * k] >> 7) & 0xFF;
        if (e >= 90 && e <= 135) ++good;
    }
    flags[0] = (good >= 96) ? 1 : 0;          // bf16 mode
    const int* w = (const int*)ei;
    int zeros = 0;
    for (int k = 0; k < 64; ++k)
        if (w[2 * k + 1] == 0) ++zeros;
    flags[1] = (zeros >= 56) ? 1 : 0;         // int64 mode
}

// ---- bucket histogram of dst>>8 ----------------------------------------
__global__ void k_count(const void* __restrict__ ei, int* __restrict__ cnt,
                        int E, int NB, const int* __restrict__ flags) {
    __shared__ int h[512];
    for (int b = threadIdx.x; b < NB; b += 256) h[b] = 0;
    __syncthreads();
    int is64 = flags[1];
    long long base = (long long)blockIdx.x * TILE_C;
    int lim = (int)min((long long)TILE_C, (long long)E - base);
    for (int k = threadIdx.x; k < lim; k += 256) {
        int d = ild(ei, (long long)E + base + k, is64);
        atomicAdd(&h[d >> 8], 1);
    }
    __syncthreads();
    for (int b = threadIdx.x; b < NB; b += 256)
        if (h[b]) atomicAdd(&cnt[b], h[b]);
}

// ---- bucket offsets (parallel scan, NB<=512) ----------------------------
// bktoff2 = exclusive scan of cnt (real edges); bktoff = scan of cnt+nloc.
__global__ void k_bscan(const int* __restrict__ cnt, int* __restrict__ bktoff2,
                        int* __restrict__ bktoff, int* __restrict__ gcur,
                        int N, int NB) {
    __shared__ int sa[512], sb[512];
    int i = threadIdx.x;
    int va = (i < NB) ? cnt[i] : 0;
    int nloc = (i < NB) ? min(256, N - (i << 8)) : 0;
    int vb = va + nloc;
    sa[i] = va; sb[i] = vb;
    __syncthreads();
    for (int d = 1; d < 512; d <<= 1) {
        int ta = (i >= d) ? sa[i - d] : 0;
        int tb = (i >= d) ? sb[i - d] : 0;
        __syncthreads();
        sa[i] += ta; sb[i] += tb;
        __syncthreads();
    }
    if (i < NB) {
        bktoff2[i] = sa[i] - va;
        bktoff[i] = sb[i] - vb;
        gcur[i] = sa[i] - va;
    }
    if (i == NB - 1) { bktoff2[NB] = sa[i]; bktoff[NB] = sb[i]; }
}

// ---- multisplit by dst bucket -------------------------------------------
__global__ void k_split(const void* __restrict__ ei, int2* __restrict__ edges2,
                        int* __restrict__ gcur, int E, int NB,
                        const int* __restrict__ flags) {
    __shared__ int hist[512], scan_[512], gbase[512], lcur[512];
    __shared__ int2 stage[TILE_S];
    int is64 = flags[1];
    long long base = (long long)blockIdx.x * TILE_S;
    int lim = (int)min((long long)TILE_S, (long long)E - base);
    for (int b = threadIdx.x; b < 512; b += 256) hist[b] = 0;
    __syncthreads();
    for (int k = threadIdx.x; k < lim; k += 256) {
        int d = ild(ei, (long long)E + base + k, is64);
        atomicAdd(&hist[d >> 8], 1);
    }
    __syncthreads();
    // parallel exclusive scan of hist (512 entries, 256 threads, Hillis-Steele)
    {
        int i0 = threadIdx.x, i1 = threadIdx.x + 256;
        scan_[i0] = hist[i0]; scan_[i1] = hist[i1];
        __syncthreads();
        for (int d = 1; d < 512; d <<= 1) {
            int t0 = (i0 >= d) ? scan_[i0 - d] : 0;
            int t1 = (i1 >= d) ? scan_[i1 - d] : 0;
            __syncthreads();
            scan_[i0] += t0; scan_[i1] += t1;
            __syncthreads();
        }
        int e0 = scan_[i0] - hist[i0];
        int e1 = scan_[i1] - hist[i1];
        __syncthreads();
        scan_[i0] = e0; scan_[i1] = e1;
        __syncthreads();
    }
    for (int b = threadIdx.x; b < NB; b += 256) {
        lcur[b] = scan_[b];
        gbase[b] = hist[b] ? atomicAdd(&gcur[b], hist[b]) : 0;
    }
    __syncthreads();
    for (int k = threadIdx.x; k < lim; k += 256) {
        int s = ild(ei, base + k, is64);
        int d = ild(ei, (long long)E + base + k, is64);
        int p = atomicAdd(&lcur[d >> 8], 1);
        stage[p] = make_int2(d, s);
    }
    __syncthreads();
    for (int t = threadIdx.x; t < lim; t += 256) {
        int2 r = stage[t];
        int b = r.x >> 8;
        edges2[gbase[b] + (t - scan_[b])] = r;
    }
}

// ---- per-bucket counting sort + fused node pass -------------------------
// Writes meta/row_ptr/dinv/xs/start. meta = src | g<<17 | min(deg,255)<<24;
// slot 0 of each row is the self record.
__global__ void k_sort(const int2* __restrict__ edges2, const void* __restrict__ batch,
                       const void* __restrict__ x, const int* __restrict__ cnt,
                       const int* __restrict__ bktoff2, const int* __restrict__ bktoff,
                       unsigned* __restrict__ meta, int* __restrict__ row_ptr,
                       float* __restrict__ dinv, float4* __restrict__ xs,
                       int* __restrict__ start, int N, int Etot,
                       const int* __restrict__ flags) {
    __shared__ int hist[256], loff[257], lcur[256], sc[256];
    __shared__ unsigned gdeg[256];
    __shared__ unsigned stage[SCAP];
    int b = blockIdx.x;
    int node0 = b << 8;
    int nloc = min(256, N - node0);
    int is64 = flags[1], isbf = flags[0];
    int i = threadIdx.x;
    if (i < nloc) hist[i] = 0;
    __syncthreads();
    int rbase = bktoff2[b], rcnt = cnt[b];
    for (int t = i; t < rcnt; t += 256) {
        int2 r = edges2[rbase + t];
        atomicAdd(&hist[r.x - node0], 1);
    }
    __syncthreads();
    // parallel exclusive scan of (hist+1)
    int v = (i < nloc) ? hist[i] + 1 : 0;
    sc[i] = v;
    __syncthreads();
    for (int d = 1; d < 256; d <<= 1) {
        int t = (i >= d) ? sc[i - d] : 0;
        __syncthreads();
        sc[i] += t;
        __syncthreads();
    }
    if (i < nloc) loff[i] = sc[i] - v;
    if (i == nloc - 1) loff[nloc] = sc[i];
    __syncthreads();
    int mbase = bktoff[b];
    if (i < nloc) {
        int node = node0 + i;
        int dg = hist[i];
        float di = rsqrtf((float)(dg + 1));
        dinv[node] = di;
        row_ptr[node] = mbase + loff[i];
        int g = ild(batch, node, is64);
        // graph boundary detection (batch sorted)
        int gp = (node == 0) ? -1 : ild(batch, node - 1, is64);
        for (int q = gp + 1; q <= g; ++q) start[q] = node;
        if (node == N - 1)
            for (int q = g + 1; q <= NGRAPH; ++q) start[q] = N;
        // xs = dinv * x
        xs[node] = make_float4(di * fld(x, 3LL * node, isbf),
                               di * fld(x, 3LL * node + 1, isbf),
                               di * fld(x, 3LL * node + 2, isbf), 0.0f);
        unsigned gd = ((unsigned)g << 17) | ((unsigned)min(dg, 255) << 24);
        gdeg[i] = gd;
        lcur[i] = loff[i] + 1;                 // slot 0 = self record
        stage[loff[i]] = (unsigned)node | gd;
    }
    __syncthreads();
    for (int t = i; t < rcnt; t += 256) {
        int2 r = edges2[rbase + t];
        int dl = r.x - node0;
        int p = atomicAdd(&lcur[dl], 1);
        if (p < SCAP) stage[p] = (unsigned)r.y | gdeg[dl];
    }
    __syncthreads();
    int total = loff[nloc];
    for (int t = i; t < total; t += 256) meta[mbase + t] = stage[t];
    if (b == 0 && i == 0) row_ptr[N] = Etot;
}

// ---- layer 1 fused: CSR gather + tiny GEMM + relu -> hs1 ----------------
// One block per dst bucket. Phase 1: thread i aggregates node node0+i's row
// (aggx in LDS). Phase 2: (i,j) mapping computes hs1 coalesced.
__global__ void k_l1(const float4* __restrict__ xs, const float* __restrict__ dinv,
                     const int* __restrict__ row_ptr, const unsigned* __restrict__ meta,
                     const void* __restrict__ W1, const void* __restrict__ b1,
                     bf16* __restrict__ hs1, int N, const int* __restrict__ flags) {
    __shared__ float w[256];        // [0..191]=W1 (3x64 row-major), [192..255]=b1
    __shared__ float ag[256][4];
    int isbf = flags[0];
    if (threadIdx.x < 192) w[threadIdx.x] = fld(W1, threadIdx.x, isbf);
    if (threadIdx.x < 64) w[192 + threadIdx.x] = fld(b1, threadIdx.x, isbf);
    int node0 = blockIdx.x << 8;
    int nloc = min(256, N - node0);
    int i = threadIdx.x;
    if (i < nloc) {
        int node = node0 + i;
        float ax = 0.f, ay = 0.f, az = 0.f;
        int p1 = row_ptr[node + 1];
        for (int p = row_ptr[node]; p < p1; ++p) {
            float4 vv = xs[meta[p] & 0x1FFFFu];
            ax += vv.x; ay += vv.y; az += vv.z;
        }
        float di = dinv[node];
        ag[i][0] = di * ax; ag[i][1] = di * ay; ag[i][2] = di * az;
        ag[i][3] = di;      // dinv for output scaling
    }
    __syncthreads();
    for (int t = threadIdx.x; t < (nloc << 6); t += 256) {
        int ii = t >> 6, j = t & 63;
        float acc = ag[ii][0] * w[j] + ag[ii][1] * w[64 + j] + ag[ii][2] * w[128 + j]
                  + w[192 + j];
        hs1[(size_t)(node0 + ii) * 64 + j] = __float2bfloat16(ag[ii][3] * fmaxf(acc, 0.0f));
    }
}

// ---- layer 2 + pool: edge-balanced meta stream (register acc) -----------
// Wave = 8 groups x 8 lanes. Group q walks edges base+q, base+q+8, ... (a
// stride-8 subsequence of the dst-sorted stream -> g stays monotone). Each
// lane loads 16B (uint4 = 8 bf16) of the 128B hs1 row: one dwordx4
// instruction fetches 8 edges' rows (1KB). Lane accumulates its 8-feature
// slice in registers; flush to P slice on g change (rare) and at end.
__global__ void k_gather2(const uint4* __restrict__ hs1q, const unsigned* __restrict__ meta,
                          float* __restrict__ P, int Etot, int chunk) {
    int wid = (blockIdx.x * blockDim.x + threadIdx.x) >> 6;
    int lane = threadIdx.x & 63;
    int q = lane >> 3;          // group 0..7
    int l8 = lane & 7;          // lane in group -> features [8*l8, 8*l8+8)
    long long base = (long long)wid * chunk;
    if (base >= Etot) return;
    long long end = base + chunk;
    if (end > Etot) end = Etot;
    float acc[8] = {0.f, 0.f, 0.f, 0.f, 0.f, 0.f, 0.f, 0.f};
    int gcur = -1;
    float* Pw = P + (size_t)(wid & (NSLICE - 1)) * (NGRAPH * 64);
#define FLUSH()                                                                 \
    if (gcur >= 0) {                                                            \
        float* dp = Pw + (size_t)gcur * 64 + (l8 << 3);                         \
        _Pragma("unroll")                                                       \
        for (int k = 0; k < 8; ++k) { atomicAdd(dp + k, acc[k]); acc[k] = 0.f; }\
    }
#define STEP(m, v)                                                              \
    {                                                                           \
        int g = (int)((m >> 17) & 0x7Fu);                                       \
        float w = rsqrtf((float)((m >> 24) & 0xFFu) + 1.0f);                    \
        if (g != gcur) { FLUSH(); gcur = g; }                                   \
        acc[0] += w * __uint_as_float(v.x << 16);                               \
        acc[1] += w * __uint_as_float(v.x & 0xFFFF0000u);                       \
        acc[2] += w * __uint_as_float(v.y << 16);                               \
        acc[3] += w * __uint_as_float(v.y & 0xFFFF0000u);                       \
        acc[4] += w * __uint_as_float(v.z << 16);                               \
        acc[5] += w * __uint_as_float(v.z & 0xFFFF0000u);                       \
        acc[6] += w * __uint_as_float(v.w << 16);                               \
        acc[7] += w * __uint_as_float(v.w & 0xFFFF0000u);                       \
    }
    long long p = base + q;
    for (; p + 24 < end; p += 32) {
        unsigned m0 = meta[p];
        unsigned m1 = meta[p + 8];
        unsigned m2 = meta[p + 16];
        unsigned m3 = meta[p + 24];
        uint4 v0 = hs1q[(size_t)(m0 & 0x1FFFFu) * 8 + l8];
        uint4 v1 = hs1q[(size_t)(m1 & 0x1FFFFu) * 8 + l8];
        uint4 v2 = hs1q[(size_t)(m2 & 0x1FFFFu) * 8 + l8];
        uint4 v3 = hs1q[(size_t)(m3 & 0x1FFFFu) * 8 + l8];
        STEP(m0, v0) STEP(m1, v1) STEP(m2, v2) STEP(m3, v3)
    }
    for (; p < end; p += 8) {
        unsigned m = meta[p];
        uint4 v = hs1q[(size_t)(m & 0x1FFFFu) * 8 + l8];
        STEP(m, v)
    }
    FLUSH();
#undef STEP
#undef FLUSH
}

// out[g][j] = (sum_slices P[g]/count_g) . W2[:,j] + b2[j]  (0 if empty graph)
__global__ void k_out(const float* __restrict__ P, const int* __restrict__ start,
                      const void* __restrict__ W2, const void* __restrict__ b2v,
                      void* __restrict__ out, const int* __restrict__ flags) {
    __shared__ float pm[64];
    int g = blockIdx.x, j = threadIdx.x;
    int isbf = flags[0];
    int c = start[g + 1] - start[g];
    if (j < 64) {
        float v = 0.f;
        for (int s = 0; s < NSLICE; ++s) v += P[(size_t)s * NGRAPH * 64 + g * 64 + j];
        pm[j] = (c > 0) ? v / (float)c : 0.0f;
    }
    __syncthreads();
    float acc = 0.0f;
    if (c > 0) {
        acc = fld(b2v, j, isbf);
        for (int k = 0; k < 64; ++k) acc += pm[k] * fld(W2, k * 128 + j, isbf);
    }
    if (isbf) ((bf16*)out)[g * 128 + j] = __float2bfloat16(acc);
    else      ((float*)out)[g * 128 + j] = acc;
}

extern "C" void kernel_launch(void* const* d_in, const int* in_sizes, int n_in,
                              void* d_out, int out_size, void* d_ws, size_t ws_size,
                              hipStream_t stream) {
    const void* x    = d_in[0];
    const void* ei   = d_in[1];   // edge_index [2,E] flat: src row then dst row
    const void* batch= d_in[2];
    const void* W1   = d_in[3];
    const void* b1   = d_in[4];
    const void* W2   = d_in[5];
    const void* b2   = d_in[6];

    const int N = in_sizes[0] / 3;
    const int E = in_sizes[1] / 2;
    const int Etot = E + N;
    const int NB = (N + 255) / 256;          // dst buckets (391)

    // ---- workspace layout (512B aligned), total ~37 MB ----
    char* ws = (char*)d_ws;
    size_t off = 0;
    auto alloc = [&](size_t bytes) {
        size_t o = off;
        off = (off + bytes + 511) & ~(size_t)511;
        return o;
    };
    int* flags    = (int*)(ws + alloc(64 * 4));
    int* cnt      = (int*)(ws + alloc((size_t)NB * 4));
    int* bktoff2  = (int*)(ws + alloc((size_t)(NB + 1) * 4));
    int* bktoff   = (int*)(ws + alloc((size_t)(NB + 1) * 4));
    int* gcur     = (int*)(ws + alloc((size_t)NB * 4));
    int* start    = (int*)(ws + alloc((size_t)(NGRAPH + 1) * 4));
    int* row_ptr  = (int*)(ws + alloc((size_t)(N + 1) * 4));
    float* dinv   = (float*)(ws + alloc((size_t)N * 4));
    int2* edges2  = (int2*)(ws + alloc((size_t)E * 8));
    unsigned* meta= (unsigned*)(ws + alloc((size_t)Etot * 4));
    float4* xs    = (float4*)(ws + alloc((size_t)N * 16));
    bf16* hs1     = (bf16*)(ws + alloc((size_t)N * 64 * 2));
    float* P      = (float*)(ws + alloc((size_t)NSLICE * NGRAPH * 64 * 4));
    (void)ws_size;

    (void)hipMemsetAsync(cnt, 0, (size_t)NB * 4, stream);
    (void)hipMemsetAsync(P, 0, (size_t)NSLICE * NGRAPH * 64 * 4, stream);

    const int cb = (E + TILE_C - 1) / TILE_C;       // 391
    const int sb = (E + TILE_S - 1) / TILE_S;       // 391

    // gather2: 2048 blocks -> 8192 waves (32/CU), edge-balanced chunks
    const int g2blocks = 2048;
    const int g2waves = g2blocks * 4;
    const int chunk = (Etot + g2waves - 1) / g2waves;

    k_detect<<<1, 64, 0, stream>>>(x, ei, flags);
    k_count<<<cb, 256, 0, stream>>>(ei, cnt, E, NB, flags);
    k_bscan<<<1, 512, 0, stream>>>(cnt, bktoff2, bktoff, gcur, N, NB);
    k_split<<<sb, 256, 0, stream>>>(ei, edges2, gcur, E, NB, flags);
    k_sort<<<NB, 256, 0, stream>>>(edges2, batch, x, cnt, bktoff2, bktoff, meta,
                                   row_ptr, dinv, xs, start, N, Etot, flags);
    k_l1<<<NB, 256, 0, stream>>>(xs, dinv, row_ptr, meta, W1, b1, hs1, N, flags);
    k_gather2<<<g2blocks, 256, 0, stream>>>((const uint4*)hs1, meta, P, Etot, chunk);
    k_out<<<NGRAPH, 128, 0, stream>>>(P, start, W2, b2, d_out, flags);
}

// Round 3
// 221.446 us; speedup vs baseline: 2.3108x; 2.3108x over previous
//
#include <hip/hip_runtime.h>
#include <hip/hip_bf16.h>

// 2-layer GCN + mean pool. N=100000, E=1600000, G=128. dims 3 -> 64 -> 128.
//   h1  = relu( (A_hat x) @ W1 + b1 )        -- aggregate 3-dim x, then tiny GEMM
//   out = (mean_g (A_hat h1)) @ W2 + b2      -- aggregate 64-dim h1, pool, tiny GEMM
//
// R12 -> R13 (flush fix):
//   R12's 8-group layout made flush atomics collide: lanes (q,l8) across the
//   8 groups hit the SAME P address when gcur is shared (99% of chunks) ->
//   8-way same-address serialization at the coherence point, WRITE_SIZE 8.3
//   -> 132.7 MB, k_gather2 60 -> 360us. Fix:
//   * final flush: if gcur wave-uniform, __shfl_xor-reduce acc across groups
//     (lanes ^8 ^16 ^32), then only q==0 lanes (8 lanes, distinct contiguous
//     addresses) issue atomics. 64x fewer atomic lane-ops.
//   * divergent/mid-stream flushes (rare graph-boundary case): slice = q so
//     concurrent group flushes never share an address.
//   Load path unchanged from R12: one dwordx4 fetches 8 edges' rows (1KB).
//
// DTYPE-ADAPTIVE: k_detect probes raw bits: flags[0]=bf16?, flags[1]=int64?

typedef __hip_bfloat16 bf16;
#define NGRAPH 128
#define NSLICE 8
#define TILE_C 4096
#define TILE_S 4096
#define SCAP   12288 // k_sort LDS stage capacity (mean 4096+256, >60 sigma)

__device__ __forceinline__ float b2f(bf16 v) { return __bfloat162float(v); }
__device__ __forceinline__ float bfb(unsigned short u) {
    return __uint_as_float((unsigned)u << 16);
}
__device__ __forceinline__ float fld(const void* p, long long i, int isbf) {
    return isbf ? b2f(((const bf16*)p)[i]) : ((const float*)p)[i];
}
__device__ __forceinline__ int ild(const void* p, long long i, int is64) {
    return is64 ? (int)((const long long*)p)[i] : ((const int*)p)[i];
}

// ---- dtype probe --------------------------------------------------------
__global__ void k_detect(const void* x, const void* ei, int* flags) {
    if (threadIdx.x != 0 || blockIdx.x != 0) return;
    const unsigned short* u = (const unsigned short*)x;
    int good = 0;
    for (int k = 0; k < 128; ++k) {
        int e = (u[2 * k] >> 7) & 0xFF;
        if (e >= 90 && e <= 135) ++good;
    }
    flags[0] = (good >= 96) ? 1 : 0;          // bf16 mode
    const int* w = (const int*)ei;
    int zeros = 0;
    for (int k = 0; k < 64; ++k)
        if (w[2 * k + 1] == 0) ++zeros;
    flags[1] = (zeros >= 56) ? 1 : 0;         // int64 mode
}

// ---- bucket histogram of dst>>8 ----------------------------------------
__global__ void k_count(const void* __restrict__ ei, int* __restrict__ cnt,
                        int E, int NB, const int* __restrict__ flags) {
    __shared__ int h[512];
    for (int b = threadIdx.x; b < NB; b += 256) h[b] = 0;
    __syncthreads();
    int is64 = flags[1];
    long long base = (long long)blockIdx.x * TILE_C;
    int lim = (int)min((long long)TILE_C, (long long)E - base);
    for (int k = threadIdx.x; k < lim; k += 256) {
        int d = ild(ei, (long long)E + base + k, is64);
        atomicAdd(&h[d >> 8], 1);
    }
    __syncthreads();
    for (int b = threadIdx.x; b < NB; b += 256)
        if (h[b]) atomicAdd(&cnt[b], h[b]);
}

// ---- bucket offsets (parallel scan, NB<=512) ----------------------------
// bktoff2 = exclusive scan of cnt (real edges); bktoff = scan of cnt+nloc.
__global__ void k_bscan(const int* __restrict__ cnt, int* __restrict__ bktoff2,
                        int* __restrict__ bktoff, int* __restrict__ gcur,
                        int N, int NB) {
    __shared__ int sa[512], sb[512];
    int i = threadIdx.x;
    int va = (i < NB) ? cnt[i] : 0;
    int nloc = (i < NB) ? min(256, N - (i << 8)) : 0;
    int vb = va + nloc;
    sa[i] = va; sb[i] = vb;
    __syncthreads();
    for (int d = 1; d < 512; d <<= 1) {
        int ta = (i >= d) ? sa[i - d] : 0;
        int tb = (i >= d) ? sb[i - d] : 0;
        __syncthreads();
        sa[i] += ta; sb[i] += tb;
        __syncthreads();
    }
    if (i < NB) {
        bktoff2[i] = sa[i] - va;
        bktoff[i] = sb[i] - vb;
        gcur[i] = sa[i] - va;
    }
    if (i == NB - 1) { bktoff2[NB] = sa[i]; bktoff[NB] = sb[i]; }
}

// ---- multisplit by dst bucket -------------------------------------------
__global__ void k_split(const void* __restrict__ ei, int2* __restrict__ edges2,
                        int* __restrict__ gcur, int E, int NB,
                        const int* __restrict__ flags) {
    __shared__ int hist[512], scan_[512], gbase[512], lcur[512];
    __shared__ int2 stage[TILE_S];
    int is64 = flags[1];
    long long base = (long long)blockIdx.x * TILE_S;
    int lim = (int)min((long long)TILE_S, (long long)E - base);
    for (int b = threadIdx.x; b < 512; b += 256) hist[b] = 0;
    __syncthreads();
    for (int k = threadIdx.x; k < lim; k += 256) {
        int d = ild(ei, (long long)E + base + k, is64);
        atomicAdd(&hist[d >> 8], 1);
    }
    __syncthreads();
    // parallel exclusive scan of hist (512 entries, 256 threads, Hillis-Steele)
    {
        int i0 = threadIdx.x, i1 = threadIdx.x + 256;
        scan_[i0] = hist[i0]; scan_[i1] = hist[i1];
        __syncthreads();
        for (int d = 1; d < 512; d <<= 1) {
            int t0 = (i0 >= d) ? scan_[i0 - d] : 0;
            int t1 = (i1 >= d) ? scan_[i1 - d] : 0;
            __syncthreads();
            scan_[i0] += t0; scan_[i1] += t1;
            __syncthreads();
        }
        int e0 = scan_[i0] - hist[i0];
        int e1 = scan_[i1] - hist[i1];
        __syncthreads();
        scan_[i0] = e0; scan_[i1] = e1;
        __syncthreads();
    }
    for (int b = threadIdx.x; b < NB; b += 256) {
        lcur[b] = scan_[b];
        gbase[b] = hist[b] ? atomicAdd(&gcur[b], hist[b]) : 0;
    }
    __syncthreads();
    for (int k = threadIdx.x; k < lim; k += 256) {
        int s = ild(ei, base + k, is64);
        int d = ild(ei, (long long)E + base + k, is64);
        int p = atomicAdd(&lcur[d >> 8], 1);
        stage[p] = make_int2(d, s);
    }
    __syncthreads();
    for (int t = threadIdx.x; t < lim; t += 256) {
        int2 r = stage[t];
        int b = r.x >> 8;
        edges2[gbase[b] + (t - scan_[b])] = r;
    }
}

// ---- per-bucket counting sort + fused node pass -------------------------
// Writes meta/row_ptr/dinv/xs/start. meta = src | g<<17 | min(deg,255)<<24;
// slot 0 of each row is the self record.
__global__ void k_sort(const int2* __restrict__ edges2, const void* __restrict__ batch,
                       const void* __restrict__ x, const int* __restrict__ cnt,
                       const int* __restrict__ bktoff2, const int* __restrict__ bktoff,
                       unsigned* __restrict__ meta, int* __restrict__ row_ptr,
                       float* __restrict__ dinv, float4* __restrict__ xs,
                       int* __restrict__ start, int N, int Etot,
                       const int* __restrict__ flags) {
    __shared__ int hist[256], loff[257], lcur[256], sc[256];
    __shared__ unsigned gdeg[256];
    __shared__ unsigned stage[SCAP];
    int b = blockIdx.x;
    int node0 = b << 8;
    int nloc = min(256, N - node0);
    int is64 = flags[1], isbf = flags[0];
    int i = threadIdx.x;
    if (i < nloc) hist[i] = 0;
    __syncthreads();
    int rbase = bktoff2[b], rcnt = cnt[b];
    for (int t = i; t < rcnt; t += 256) {
        int2 r = edges2[rbase + t];
        atomicAdd(&hist[r.x - node0], 1);
    }
    __syncthreads();
    // parallel exclusive scan of (hist+1)
    int v = (i < nloc) ? hist[i] + 1 : 0;
    sc[i] = v;
    __syncthreads();
    for (int d = 1; d < 256; d <<= 1) {
        int t = (i >= d) ? sc[i - d] : 0;
        __syncthreads();
        sc[i] += t;
        __syncthreads();
    }
    if (i < nloc) loff[i] = sc[i] - v;
    if (i == nloc - 1) loff[nloc] = sc[i];
    __syncthreads();
    int mbase = bktoff[b];
    if (i < nloc) {
        int node = node0 + i;
        int dg = hist[i];
        float di = rsqrtf((float)(dg + 1));
        dinv[node] = di;
        row_ptr[node] = mbase + loff[i];
        int g = ild(batch, node, is64);
        // graph boundary detection (batch sorted)
        int gp = (node == 0) ? -1 : ild(batch, node - 1, is64);
        for (int q = gp + 1; q <= g; ++q) start[q] = node;
        if (node == N - 1)
            for (int q = g + 1; q <= NGRAPH; ++q) start[q] = N;
        // xs = dinv * x
        xs[node] = make_float4(di * fld(x, 3LL * node, isbf),
                               di * fld(x, 3LL * node + 1, isbf),
                               di * fld(x, 3LL * node + 2, isbf), 0.0f);
        unsigned gd = ((unsigned)g << 17) | ((unsigned)min(dg, 255) << 24);
        gdeg[i] = gd;
        lcur[i] = loff[i] + 1;                 // slot 0 = self record
        stage[loff[i]] = (unsigned)node | gd;
    }
    __syncthreads();
    for (int t = i; t < rcnt; t += 256) {
        int2 r = edges2[rbase + t];
        int dl = r.x - node0;
        int p = atomicAdd(&lcur[dl], 1);
        if (p < SCAP) stage[p] = (unsigned)r.y | gdeg[dl];
    }
    __syncthreads();
    int total = loff[nloc];
    for (int t = i; t < total; t += 256) meta[mbase + t] = stage[t];
    if (b == 0 && i == 0) row_ptr[N] = Etot;
}

// ---- layer 1 fused: CSR gather + tiny GEMM + relu -> hs1 ----------------
// One block per dst bucket. Phase 1: thread i aggregates node node0+i's row
// (aggx in LDS). Phase 2: (i,j) mapping computes hs1 coalesced.
__global__ void k_l1(const float4* __restrict__ xs, const float* __restrict__ dinv,
                     const int* __restrict__ row_ptr, const unsigned* __restrict__ meta,
                     const void* __restrict__ W1, const void* __restrict__ b1,
                     bf16* __restrict__ hs1, int N, const int* __restrict__ flags) {
    __shared__ float w[256];        // [0..191]=W1 (3x64 row-major), [192..255]=b1
    __shared__ float ag[256][4];
    int isbf = flags[0];
    if (threadIdx.x < 192) w[threadIdx.x] = fld(W1, threadIdx.x, isbf);
    if (threadIdx.x < 64) w[192 + threadIdx.x] = fld(b1, threadIdx.x, isbf);
    int node0 = blockIdx.x << 8;
    int nloc = min(256, N - node0);
    int i = threadIdx.x;
    if (i < nloc) {
        int node = node0 + i;
        float ax = 0.f, ay = 0.f, az = 0.f;
        int p1 = row_ptr[node + 1];
        for (int p = row_ptr[node]; p < p1; ++p) {
            float4 vv = xs[meta[p] & 0x1FFFFu];
            ax += vv.x; ay += vv.y; az += vv.z;
        }
        float di = dinv[node];
        ag[i][0] = di * ax; ag[i][1] = di * ay; ag[i][2] = di * az;
        ag[i][3] = di;      // dinv for output scaling
    }
    __syncthreads();
    for (int t = threadIdx.x; t < (nloc << 6); t += 256) {
        int ii = t >> 6, j = t & 63;
        float acc = ag[ii][0] * w[j] + ag[ii][1] * w[64 + j] + ag[ii][2] * w[128 + j]
                  + w[192 + j];
        hs1[(size_t)(node0 + ii) * 64 + j] = __float2bfloat16(ag[ii][3] * fmaxf(acc, 0.0f));
    }
}

// ---- layer 2 + pool: edge-balanced meta stream (register acc) -----------
// Wave = 8 groups x 8 lanes. Group q walks edges base+q, base+q+8, ... (a
// stride-8 subsequence of the dst-sorted stream -> g stays monotone). Each
// lane loads 16B (uint4 = 8 bf16) of the 128B hs1 row: one dwordx4
// instruction fetches 8 edges' rows (1KB). Lane accumulates its 8-feature
// slice in registers.
// FLUSH discipline (avoids same-address atomic collisions; see R13 note):
//   * mid-stream (g change, rare): per-group divergent flush into slice q --
//     concurrently flushing groups never share an address.
//   * final: if gcur wave-uniform (common), shuffle-reduce across groups
//     (lanes ^8 ^16 ^32) then 8 lanes issue 8 atomics each, all distinct.
__global__ void k_gather2(const uint4* __restrict__ hs1q, const unsigned* __restrict__ meta,
                          float* __restrict__ P, int Etot, int chunk) {
    int wid = (blockIdx.x * blockDim.x + threadIdx.x) >> 6;
    int lane = threadIdx.x & 63;
    int q = lane >> 3;          // group 0..7
    int l8 = lane & 7;          // lane in group -> features [8*l8, 8*l8+8)
    long long base = (long long)wid * chunk;
    if (base >= Etot) return;
    long long end = base + chunk;
    if (end > Etot) end = Etot;
    float acc[8] = {0.f, 0.f, 0.f, 0.f, 0.f, 0.f, 0.f, 0.f};
    int gcur = -1;
// divergent flush: slice = q so no two groups ever share an address
#define GFLUSH()                                                                \
    if (gcur >= 0) {                                                            \
        float* dp = P + (size_t)q * (NGRAPH * 64) + (size_t)gcur * 64 + (l8 << 3); \
        _Pragma("unroll")                                                       \
        for (int k = 0; k < 8; ++k) { atomicAdd(dp + k, acc[k]); acc[k] = 0.f; }\
    }
#define STEP(m, v)                                                              \
    {                                                                           \
        int g = (int)((m >> 17) & 0x7Fu);                                       \
        float w = rsqrtf((float)((m >> 24) & 0xFFu) + 1.0f);                    \
        if (g != gcur) { GFLUSH(); gcur = g; }                                  \
        acc[0] += w * __uint_as_float(v.x << 16);                               \
        acc[1] += w * __uint_as_float(v.x & 0xFFFF0000u);                       \
        acc[2] += w * __uint_as_float(v.y << 16);                               \
        acc[3] += w * __uint_as_float(v.y & 0xFFFF0000u);                       \
        acc[4] += w * __uint_as_float(v.z << 16);                               \
        acc[5] += w * __uint_as_float(v.z & 0xFFFF0000u);                       \
        acc[6] += w * __uint_as_float(v.w << 16);                               \
        acc[7] += w * __uint_as_float(v.w & 0xFFFF0000u);                       \
    }
    long long p = base + q;
    for (; p + 24 < end; p += 32) {
        unsigned m0 = meta[p];
        unsigned m1 = meta[p + 8];
        unsigned m2 = meta[p + 16];
        unsigned m3 = meta[p + 24];
        uint4 v0 = hs1q[(size_t)(m0 & 0x1FFFFu) * 8 + l8];
        uint4 v1 = hs1q[(size_t)(m1 & 0x1FFFFu) * 8 + l8];
        uint4 v2 = hs1q[(size_t)(m2 & 0x1FFFFu) * 8 + l8];
        uint4 v3 = hs1q[(size_t)(m3 & 0x1FFFFu) * 8 + l8];
        STEP(m0, v0) STEP(m1, v1) STEP(m2, v2) STEP(m3, v3)
    }
    for (; p < end; p += 8) {
        unsigned m = meta[p];
        uint4 v = hs1q[(size_t)(m & 0x1FFFFu) * 8 + l8];
        STEP(m, v)
    }
    // final flush
    {
        int g0 = __shfl(gcur, 0);
        if (g0 >= 0 && __all(gcur == g0)) {
            // reduce acc across the 8 groups (lane bits 3..5), then 8 lanes write
#pragma unroll
            for (int k = 0; k < 8; ++k) {
                acc[k] += __shfl_xor(acc[k], 8);
                acc[k] += __shfl_xor(acc[k], 16);
                acc[k] += __shfl_xor(acc[k], 32);
            }
            if (q == 0) {
                float* dp = P + (size_t)(wid & (NSLICE - 1)) * (NGRAPH * 64)
                              + (size_t)g0 * 64 + (l8 << 3);
#pragma unroll
                for (int k = 0; k < 8; ++k) atomicAdd(dp + k, acc[k]);
            }
        } else {
            GFLUSH();
        }
    }
#undef STEP
#undef GFLUSH
}

// out[g][j] = (sum_slices P[g]/count_g) . W2[:,j] + b2[j]  (0 if empty graph)
__global__ void k_out(const float* __restrict__ P, const int* __restrict__ start,
                      const void* __restrict__ W2, const void* __restrict__ b2v,
                      void* __restrict__ out, const int* __restrict__ flags) {
    __shared__ float pm[64];
    int g = blockIdx.x, j = threadIdx.x;
    int isbf = flags[0];
    int c = start[g + 1] - start[g];
    if (j < 64) {
        float v = 0.f;
        for (int s = 0; s < NSLICE; ++s) v += P[(size_t)s * NGRAPH * 64 + g * 64 + j];
        pm[j] = (c > 0) ? v / (float)c : 0.0f;
    }
    __syncthreads();
    float acc = 0.0f;
    if (c > 0) {
        acc = fld(b2v, j, isbf);
        for (int k = 0; k < 64; ++k) acc += pm[k] * fld(W2, k * 128 + j, isbf);
    }
    if (isbf) ((bf16*)out)[g * 128 + j] = __float2bfloat16(acc);
    else      ((float*)out)[g * 128 + j] = acc;
}

extern "C" void kernel_launch(void* const* d_in, const int* in_sizes, int n_in,
                              void* d_out, int out_size, void* d_ws, size_t ws_size,
                              hipStream_t stream) {
    const void* x    = d_in[0];
    const void* ei   = d_in[1];   // edge_index [2,E] flat: src row then dst row
    const void* batch= d_in[2];
    const void* W1   = d_in[3];
    const void* b1   = d_in[4];
    const void* W2   = d_in[5];
    const void* b2   = d_in[6];

    const int N = in_sizes[0] / 3;
    const int E = in_sizes[1] / 2;
    const int Etot = E + N;
    const int NB = (N + 255) / 256;          // dst buckets (391)

    // ---- workspace layout (512B aligned), total ~37 MB ----
    char* ws = (char*)d_ws;
    size_t off = 0;
    auto alloc = [&](size_t bytes) {
        size_t o = off;
        off = (off + bytes + 511) & ~(size_t)511;
        return o;
    };
    int* flags    = (int*)(ws + alloc(64 * 4));
    int* cnt      = (int*)(ws + alloc((size_t)NB * 4));
    int* bktoff2  = (int*)(ws + alloc((size_t)(NB + 1) * 4));
    int* bktoff   = (int*)(ws + alloc((size_t)(NB + 1) * 4));
    int* gcur     = (int*)(ws + alloc((size_t)NB * 4));
    int* start    = (int*)(ws + alloc((size_t)(NGRAPH + 1) * 4));
    int* row_ptr  = (int*)(ws + alloc((size_t)(N + 1) * 4));
    float* dinv   = (float*)(ws + alloc((size_t)N * 4));
    int2* edges2  = (int2*)(ws + alloc((size_t)E * 8));
    unsigned* meta= (unsigned*)(ws + alloc((size_t)Etot * 4));
    float4* xs    = (float4*)(ws + alloc((size_t)N * 16));
    bf16* hs1     = (bf16*)(ws + alloc((size_t)N * 64 * 2));
    float* P      = (float*)(ws + alloc((size_t)NSLICE * NGRAPH * 64 * 4));
    (void)ws_size;

    (void)hipMemsetAsync(cnt, 0, (size_t)NB * 4, stream);
    (void)hipMemsetAsync(P, 0, (size_t)NSLICE * NGRAPH * 64 * 4, stream);

    const int cb = (E + TILE_C - 1) / TILE_C;       // 391
    const int sb = (E + TILE_S - 1) / TILE_S;       // 391

    // gather2: 2048 blocks -> 8192 waves (32/CU), edge-balanced chunks
    const int g2blocks = 2048;
    const int g2waves = g2blocks * 4;
    const int chunk = (Etot + g2waves - 1) / g2waves;

    k_detect<<<1, 64, 0, stream>>>(x, ei, flags);
    k_count<<<cb, 256, 0, stream>>>(ei, cnt, E, NB, flags);
    k_bscan<<<1, 512, 0, stream>>>(cnt, bktoff2, bktoff, gcur, N, NB);
    k_split<<<sb, 256, 0, stream>>>(ei, edges2, gcur, E, NB, flags);
    k_sort<<<NB, 256, 0, stream>>>(edges2, batch, x, cnt, bktoff2, bktoff, meta,
                                   row_ptr, dinv, xs, start, N, Etot, flags);
    k_l1<<<NB, 256, 0, stream>>>(xs, dinv, row_ptr, meta, W1, b1, hs1, N, flags);
    k_gather2<<<g2blocks, 256, 0, stream>>>((const uint4*)hs1, meta, P, Etot, chunk);
    k_out<<<NGRAPH, 128, 0, stream>>>(P, start, W2, b2, d_out, flags);
}